// Round 16
// baseline (65.675 us; speedup 1.0000x reference)
//
#include <hip/hip_runtime.h>

// AffinitySideLoss: B=4, E=12, H=W=512, S=8 offsets, output = 1 float scalar.
// d_in[0] = input_ float32 [4,12,512,512]
// d_in[1] = target int32   [4,1,512,512]
// d_in[2] = offsets int32  [8,2]  (values in [-27,0))
// d_out   = float32 [1]
// d_ws    = per-block partials: float [16][1024]  (64 KB)
//
// R16 = R15 + DOUBLE-buffered LDS -> ONE __syncthreads per channel (13 vs
// 26). Per iter: load(e+1) -> regs (flies under compute), compute(e) from
// buf[e&1], write(e+1) -> buf[(e+1)&1] (vmcnt wait covered by compute),
// barrier (vm queue empty at this point, so __syncthreads' vmcnt(0) drain
// is harmless - no raw-barrier codegen risk). 16x64 tile, 1024 blocks,
// 4 blocks/CU. R15 analysis: LDS variants are serialization-bound (fill
// floor ~19us of the observed ~40), so halving barriers is the lever.

typedef float f2 __attribute__((ext_vector_type(2)));
typedef float f4 __attribute__((ext_vector_type(4)));

#define HWSZ   262144     // 512*512
#define NE     12
#define NC     13         // 12 emb channels + 1 seg channel
#define NS     8
#define TROWS  16
#define TCOLS  64
#define NBLK   1024       // 4 batches x 32 row-tiles x 8 col-tiles
#define HROWS  44         // rows r0-28 .. r0+15
#define HCOLS  92         // cols c0-28 .. c0+63
#define HSZ    (HROWS * HCOLS)   // 4048 floats
#define NCHUNK (HCOLS / 4)       // 23 f4-chunks per halo row
#define NSLOT  (HSZ / 4)         // 1012 f4 slots

__global__ __launch_bounds__(512) void affloss_main(
    const float* __restrict__ emb, const int* __restrict__ seg,
    const int* __restrict__ offs, float* __restrict__ partial) {
  __shared__ f4 buf4[2][NSLOT];         // 2 x 16,192 B = 32,384 B
  __shared__ float red[8][16];

  // XCD swizzle (bijective, 1024 % 8 == 0): contiguous tile band per XCD so
  // neighbor-tile halo overlap hits that XCD's L2.
  const int bid = blockIdx.x;
  const int nb  = (bid & 7) * (NBLK / 8) + (bid >> 3);
  const int b   = nb >> 8;              // batch 0..3
  const int rem = nb & 255;             // 32 row-tiles x 8 col-tiles
  const int r0  = (rem >> 3) * TROWS;   // 0..496
  const int c0  = (rem & 7) * TCOLS;    // 0..448

  const int tid = threadIdx.x;
  const int tx  = tid & 31;             // f2 col: tile cols 2tx, 2tx+1
  const int row = tid >> 5;             // tile row 0..15
  const int wv  = tid >> 6;             // wave 0..7

  const float* embB = emb + (size_t)b * NE * HWSZ;
  const int*   segB = seg + (size_t)b * HWSZ;

  int oyv[NS], oxv[NS];
  #pragma unroll
  for (int s = 0; s < NS; ++s) { oyv[s] = offs[2 * s]; oxv[s] = offs[2 * s + 1]; }

  // Per-thread staging geometry: slots tid, tid+512 (2nd only for tid<500).
  // slot -> halo (row, 4-col chunk); global row clamps at 0 (replication);
  // negative col chunk (c0==0, cols<28) is entirely col<0 -> splat col 0.
  int srow[2], sgc[2];
  #pragma unroll
  for (int k = 0; k < 2; ++k) {
    const int slot = tid + k * 512;
    const int rr = slot / NCHUNK;
    const int ch = slot - rr * NCHUNK;
    int gr = r0 - 28 + rr; gr = gr < 0 ? 0 : gr;
    srow[k] = gr;
    sgc[k] = c0 - 28 + 4 * ch;
  }
  const bool s1 = tid < (NSLOT - 512);   // threads 0..499 own a 2nd slot

  auto stage_load = [&](int e, f4* r) {
    const float* p = (e < NE) ? (embB + (size_t)e * HWSZ) : (const float*)segB;
    #pragma unroll
    for (int k = 0; k < 2; ++k) {
      if (k == 1 && !s1) continue;
      const float* rowp = p + srow[k] * 512;
      if (sgc[k] >= 0) {
        r[k] = *reinterpret_cast<const f4*>(rowp + sgc[k]);   // 16B aligned
      } else {
        const float v = rowp[0];                              // replication splat
        r[k] = f4{v, v, v, v};
      }
    }
  };
  auto stage_write = [&](int bi, const f4* r) {
    buf4[bi][tid] = r[0];                                     // ds_write_b128
    if (s1) buf4[bi][tid + 512] = r[1];
  };

  f2 ssv[NS];
  #pragma unroll
  for (int s = 0; s < NS; ++s) ssv[s] = f2{0.f, 0.f};
  float numa[NS], dena[NS];
  #pragma unroll
  for (int s = 0; s < NS; ++s) { numa[s] = 0.f; dena[s] = 0.f; }

  const int cb = (row + 28) * HCOLS + 28 + 2 * tx;   // center px0 idx (8B aligned)

  f4 r[2];
  stage_load(0, r);
  stage_write(0, r);                   // vmcnt wait (one exposed latency)
  __syncthreads();

  for (int e = 0; e < NC; ++e) {
    if (e + 1 < NC) stage_load(e + 1, r);   // issued now, lands under compute
    const float* buf = (const float*)buf4[e & 1];

    if (e < NE) {
      const f2 cc = *reinterpret_cast<const f2*>(buf + cb);
      #pragma unroll
      for (int s = 0; s < NS; ++s) {
        const int a = cb + oyv[s] * HCOLS + oxv[s];   // in-halo by constr.
        f2 sh; sh[0] = buf[a]; sh[1] = buf[a + 1];
        const f2 d = cc - sh;
        ssv[s][0] = fmaf(d[0], d[0], ssv[s][0]);
        ssv[s][1] = fmaf(d[1], d[1], ssv[s][1]);
      }
    } else {
      // seg channel: bit-exact int compare + dice accumulation
      const int tc0 = __float_as_int(buf[cb]);
      const int tc1 = __float_as_int(buf[cb + 1]);
      #pragma unroll
      for (int s = 0; s < NS; ++s) {
        const int a = cb + oyv[s] * HCOLS + oxv[s];
        const int t0 = __float_as_int(buf[a]);
        const int t1 = __float_as_int(buf[a + 1]);
        {
          const float n  = __builtin_amdgcn_sqrtf(ssv[s][0]);
          const float rc = fmaxf(fmaf(n, -(1.0f / 3.0f), 1.0f), 0.0f);
          const float A  = fmaf(-rc, rc, 1.0f);
          const float ta = (tc0 == t0) ? 0.f : 1.f;
          numa[s] = fmaf(A, ta, numa[s]);
          dena[s] += fmaf(A, A, ta);
        }
        {
          const float n  = __builtin_amdgcn_sqrtf(ssv[s][1]);
          const float rc = fmaxf(fmaf(n, -(1.0f / 3.0f), 1.0f), 0.0f);
          const float A  = fmaf(-rc, rc, 1.0f);
          const float ta = (tc1 == t1) ? 0.f : 1.f;
          numa[s] = fmaf(A, ta, numa[s]);
          dena[s] += fmaf(A, A, ta);
        }
      }
    }

    if (e + 1 < NC) {
      stage_write((e + 1) & 1, r);     // vmcnt wait covered by compute above
      __syncthreads();                 // vm queue empty here -> drain harmless
    }
  }

  // block reduction: [0..7]=num, [8..15]=den
  float arr[16];
  #pragma unroll
  for (int s = 0; s < NS; ++s) { arr[s] = numa[s]; arr[8 + s] = dena[s]; }
  #pragma unroll
  for (int k = 0; k < 16; ++k) {
    float v = arr[k];
    #pragma unroll
    for (int o = 32; o > 0; o >>= 1) v += __shfl_down(v, o, 64);
    arr[k] = v;
  }
  const int lane = tid & 63;
  if (lane == 0) {
    #pragma unroll
    for (int k = 0; k < 16; ++k) red[wv][k] = arr[k];
  }
  __syncthreads();
  if (tid < 16) {
    float v = 0.f;
    #pragma unroll
    for (int w = 0; w < 8; ++w) v += red[w][tid];
    partial[tid * NBLK + blockIdx.x] = v;   // [channel][block]
  }
}

__global__ __launch_bounds__(1024) void affloss_final(
    const float* __restrict__ partial, float* __restrict__ out) {
  __shared__ double csum[16];
  const int lane = threadIdx.x & 63, wv = threadIdx.x >> 6;  // wv = channel

  double s = 0.0;
  for (int i = lane; i < NBLK; i += 64)
    s += (double)partial[wv * NBLK + i];
  #pragma unroll
  for (int o = 32; o > 0; o >>= 1) s += __shfl_down(s, o, 64);
  if (lane == 0) csum[wv] = s;
  __syncthreads();

  if (threadIdx.x == 0) {
    double total = 0.0;
    #pragma unroll
    for (int c = 0; c < 8; ++c) {
      double num = csum[c];
      double den = csum[8 + c];
      if (den < 1e-7) den = 1e-7;            // maximum(den, EPS)
      total += 1.0 - 2.0 * num / den;
    }
    out[0] = (float)total;
  }
}

extern "C" void kernel_launch(void* const* d_in, const int* in_sizes, int n_in,
                              void* d_out, int out_size, void* d_ws, size_t ws_size,
                              hipStream_t stream) {
  const float* emb  = (const float*)d_in[0];
  const int*   seg  = (const int*)d_in[1];
  const int*   offs = (const int*)d_in[2];
  float* partial = (float*)d_ws;   // 16*1024 floats = 65,536 B

  affloss_main<<<NBLK, 512, 0, stream>>>(emb, seg, offs, partial);
  affloss_final<<<1, 1024, 0, stream>>>(partial, (float*)d_out);
}

// Round 17
// 40.478 us; speedup vs baseline: 1.6225x; 1.6225x over previous
//
#include <hip/hip_runtime.h>

// AffinitySideLoss: B=4, E=12, H=W=512, S=8 offsets, output = 1 float scalar.
// d_in[0] = input_ float32 [4,12,512,512]
// d_in[1] = target int32   [4,1,512,512]
// d_in[2] = offsets int32  [8,2]  (values in [-27,0))
// d_out   = float32 [1]
// d_ws    = per-block partials: float [16][1024]  (64 KB)
//
// R17 = R15's proven schedule (single LDS buffer, 2 barriers/channel, load
// issued after the barriers -> short live range, VGPR 32 there) with a
// conflict-free lane geometry: lane = column (stride 4B -> zero LDS bank
// conflicts; R15's f2-per-thread stride-8B pattern was 4-way = the 3.4M
// SQ_LDS_BANK_CONFLICT), thread owns 4 rows {w,w+4,w+8,w+12} -> per sample
// one address add + 4 ds_read_b32 at constant offsets (1472*q, folded into
// the 16-bit ds offset immediate). Staging: 4 f4 slots/thread, contiguous
// b128 global loads AND LDS writes (optimal patterns). 1024 blocks x 256
// thr -> 6+ blocks/CU.

typedef float f4 __attribute__((ext_vector_type(4)));

#define HWSZ   262144     // 512*512
#define NE     12
#define NC     13         // 12 emb channels + 1 seg channel
#define NS     8
#define TROWS  16
#define TCOLS  64
#define NBLK   1024       // 4 batches x 32 row-tiles x 8 col-tiles
#define HROWS  44         // rows r0-28 .. r0+15
#define HCOLS  92         // cols c0-28 .. c0+63
#define HSZ    (HROWS * HCOLS)   // 4048 floats
#define NCHUNK (HCOLS / 4)       // 23 f4-chunks per halo row
#define NSLOT  (HSZ / 4)         // 1012 f4 slots
#define QSTEP  (4 * HCOLS)       // 368 floats between a thread's rows

__global__ __launch_bounds__(256) void affloss_main(
    const float* __restrict__ emb, const int* __restrict__ seg,
    const int* __restrict__ offs, float* __restrict__ partial) {
  __shared__ f4 buf4[NSLOT];            // 16,192 B halo buffer
  __shared__ float red[4][16];
  const float* buf = (const float*)buf4;

  // XCD swizzle (bijective, 1024 % 8 == 0): contiguous tile band per XCD.
  const int bid = blockIdx.x;
  const int nb  = (bid & 7) * (NBLK / 8) + (bid >> 3);
  const int b   = nb >> 8;              // batch 0..3
  const int rem = nb & 255;             // 32 row-tiles x 8 col-tiles
  const int r0  = (rem >> 3) * TROWS;   // 0..496
  const int c0  = (rem & 7) * TCOLS;    // 0..448

  const int tid  = threadIdx.x;
  const int lane = tid & 63;            // column within tile (stride 4B!)
  const int w    = tid >> 6;            // wave 0..3 -> rows w,w+4,w+8,w+12

  const float* embB = emb + (size_t)b * NE * HWSZ;
  const int*   segB = seg + (size_t)b * HWSZ;

  int soff[NS];                         // halo-space offsets (uniform -> SGPR)
  #pragma unroll
  for (int s = 0; s < NS; ++s)
    soff[s] = offs[2 * s] * HCOLS + offs[2 * s + 1];

  // Staging geometry: f4 slots tid + k*256 (k=0..3; k==3 only tid<244).
  // slot -> halo (row, 4-col chunk); row clamps at 0 (replication); fully-
  // negative col chunk (c0==0, cols<28) splats col 0.
  int srow[4], sgc[4];
  #pragma unroll
  for (int k = 0; k < 4; ++k) {
    const int slot = tid + k * 256;
    const int rr = slot / NCHUNK;
    const int ch = slot - rr * NCHUNK;
    int gr = r0 - 28 + rr; gr = gr < 0 ? 0 : gr;
    srow[k] = gr;
    sgc[k] = c0 - 28 + 4 * ch;
  }
  const bool s3 = tid < (NSLOT - 3 * 256);   // threads 0..243 own slot 4

  auto stage_load = [&](int e, f4* r) {
    const float* p = (e < NE) ? (embB + (size_t)e * HWSZ) : (const float*)segB;
    #pragma unroll
    for (int k = 0; k < 4; ++k) {
      if (k == 3 && !s3) continue;
      const float* rowp = p + srow[k] * 512;
      if (sgc[k] >= 0) {
        r[k] = *reinterpret_cast<const f4*>(rowp + sgc[k]);   // 16B aligned
      } else {
        const float v = rowp[0];                              // replication splat
        r[k] = f4{v, v, v, v};
      }
    }
  };
  auto stage_write = [&](const f4* r) {
    #pragma unroll
    for (int k = 0; k < 4; ++k) {
      if (k == 3 && !s3) continue;
      buf4[tid + k * 256] = r[k];       // contiguous b128 (optimal pattern)
    }
  };

  float ssv[4][NS];                     // per-row-q, per-sample sum of squares
  #pragma unroll
  for (int q = 0; q < 4; ++q)
    #pragma unroll
    for (int s = 0; s < NS; ++s) ssv[q][s] = 0.f;
  float numa[NS], dena[NS];
  #pragma unroll
  for (int s = 0; s < NS; ++s) { numa[s] = 0.f; dena[s] = 0.f; }

  // center px index for q=0: halo row (28+w), halo col (28+lane)
  const int cb0 = (28 + w) * HCOLS + 28 + lane;

  f4 r[4];
  stage_load(0, r);

  for (int e = 0; e < NC; ++e) {
    __syncthreads();                   // readers of buf (channel e-1) done
    stage_write(r);                    // waits only on r's loads (vmcnt)
    __syncthreads();                   // writes visible
    if (e + 1 < NC) stage_load(e + 1, r);   // flies during compute below

    if (e < NE) {
      float cc[4];
      #pragma unroll
      for (int q = 0; q < 4; ++q) cc[q] = buf[cb0 + QSTEP * q];
      #pragma unroll
      for (int s = 0; s < NS; ++s) {
        const int a = cb0 + soff[s];   // one VALU add; +QSTEP*q is ds imm
        #pragma unroll
        for (int q = 0; q < 4; ++q) {
          const float sh = buf[a + QSTEP * q];
          const float d = cc[q] - sh;
          ssv[q][s] = fmaf(d, d, ssv[q][s]);
        }
      }
    } else {
      // seg channel: bit-exact int compare + dice accumulation
      int tc[4];
      #pragma unroll
      for (int q = 0; q < 4; ++q) tc[q] = __float_as_int(buf[cb0 + QSTEP * q]);
      #pragma unroll
      for (int s = 0; s < NS; ++s) {
        const int a = cb0 + soff[s];
        #pragma unroll
        for (int q = 0; q < 4; ++q) {
          const int t = __float_as_int(buf[a + QSTEP * q]);
          const float n  = __builtin_amdgcn_sqrtf(ssv[q][s]);
          const float rc = fmaxf(fmaf(n, -(1.0f / 3.0f), 1.0f), 0.0f);
          const float A  = fmaf(-rc, rc, 1.0f);
          const float ta = (tc[q] == t) ? 0.f : 1.f;
          numa[s] = fmaf(A, ta, numa[s]);
          dena[s] += fmaf(A, A, ta);
        }
      }
    }
  }

  // block reduction: [0..7]=num, [8..15]=den
  float arr[16];
  #pragma unroll
  for (int s = 0; s < NS; ++s) { arr[s] = numa[s]; arr[8 + s] = dena[s]; }
  #pragma unroll
  for (int k = 0; k < 16; ++k) {
    float v = arr[k];
    #pragma unroll
    for (int o = 32; o > 0; o >>= 1) v += __shfl_down(v, o, 64);
    arr[k] = v;
  }
  if (lane == 0) {
    #pragma unroll
    for (int k = 0; k < 16; ++k) red[w][k] = arr[k];
  }
  __syncthreads();
  if (tid < 16) {
    float v = red[0][tid] + red[1][tid] + red[2][tid] + red[3][tid];
    partial[tid * NBLK + blockIdx.x] = v;   // [channel][block]
  }
}

__global__ __launch_bounds__(1024) void affloss_final(
    const float* __restrict__ partial, float* __restrict__ out) {
  __shared__ double csum[16];
  const int lane = threadIdx.x & 63, wv = threadIdx.x >> 6;  // wv = channel

  double s = 0.0;
  for (int i = lane; i < NBLK; i += 64)
    s += (double)partial[wv * NBLK + i];
  #pragma unroll
  for (int o = 32; o > 0; o >>= 1) s += __shfl_down(s, o, 64);
  if (lane == 0) csum[wv] = s;
  __syncthreads();

  if (threadIdx.x == 0) {
    double total = 0.0;
    #pragma unroll
    for (int c = 0; c < 8; ++c) {
      double num = csum[c];
      double den = csum[8 + c];
      if (den < 1e-7) den = 1e-7;            // maximum(den, EPS)
      total += 1.0 - 2.0 * num / den;
    }
    out[0] = (float)total;
  }
}

extern "C" void kernel_launch(void* const* d_in, const int* in_sizes, int n_in,
                              void* d_out, int out_size, void* d_ws, size_t ws_size,
                              hipStream_t stream) {
  const float* emb  = (const float*)d_in[0];
  const int*   seg  = (const int*)d_in[1];
  const int*   offs = (const int*)d_in[2];
  float* partial = (float*)d_ws;   // 16*1024 floats = 65,536 B

  affloss_main<<<NBLK, 256, 0, stream>>>(emb, seg, offs, partial);
  affloss_final<<<1, 1024, 0, stream>>>(partial, (float*)d_out);
}